// Round 1
// 126.032 us; speedup vs baseline: 1.0081x; 1.0081x over previous
//
#include <hip/hip_runtime.h>
#include <math.h>

#define NPAIR  2
#define KDIM   64
#define NKP    400
#define NTILE  28            /* keypoint 16-tiles (448 padded) */
#define HWPIX  65536
#define MREF   70.0f         /* fixed softmax reference: logits = 100*cos <= 100 */
#define LOG2E  1.44269504f
#define MBLK   256           /* match blocks per pair: 256 pixels = one image row */

/* ws layout (dwords):
   [0, BFRAG_DW)  : tgt B-fragments [p][nt][ks][hi/lo][lane][4dw], bf16 pairs
   [BFRAG_DW, ..) : partials [p][nt][256 mb][16 j] float2 {S, U(full-row u)} */
#define BFRAG_DW (NPAIR*NTILE*2*2*256)   /* 57344 dwords */

using frag_ab = __attribute__((ext_vector_type(8))) short;   // 8 bf16
using f32x4   = __attribute__((ext_vector_type(4))) float;

__device__ __forceinline__ unsigned short f2bf(float f){
    unsigned u = __builtin_bit_cast(unsigned, f);
    u += 0x7fffu + ((u >> 16) & 1u);          // round-to-nearest-even
    return (unsigned short)(u >> 16);
}
__device__ __forceinline__ float bf2f(unsigned short h){
    unsigned u = ((unsigned)h) << 16;
    return __builtin_bit_cast(float, u);
}

/* normalize tgt desc, split to bf16 hi/lo, store in MFMA B-frag order
   (n = lane&15, k = (lane>>4)*8 + j). */
__global__ __launch_bounds__(256) void prep_kernel(
    const float* __restrict__ ksc, const float* __restrict__ kd,
    const int* __restrict__ tgt_ids, const int* __restrict__ src_ids,
    unsigned* __restrict__ wsu, float* __restrict__ out)
{
    __shared__ float xs[KDIM][33];
    __shared__ float inv_s[32];
    int d = blockIdx.x, p = blockIdx.y, t = threadIdx.x;
    int tgt = tgt_ids[p];
    int nl = t & 31, c0 = t >> 5;
    #pragma unroll
    for (int cc = 0; cc < 8; ++cc){
        int c = cc*8 + c0;
        int n = d*32 + nl;
        xs[c][nl] = (n < NKP) ? kd[(tgt*KDIM + c)*NKP + n] : 0.f;
    }
    __syncthreads();
    if (t < 32){
        float s = 0.f;
        #pragma unroll
        for (int c = 0; c < KDIM; ++c){ float v = xs[c][t]; s = fmaf(v, v, s); }
        inv_s[t] = 1.f / fmaxf(sqrtf(s), 1e-12f);
    }
    __syncthreads();
    {
        int l = t & 63, rk = t >> 6;
        int rt = rk >> 1, ks = rk & 1;
        int cl = l & 15, g = l >> 4;
        int nloc = rt*16 + cl;
        float inv = inv_s[nloc];
        int k0 = ks*32 + g*8;
        unsigned hu[4], lu[4];
        #pragma unroll
        for (int j2 = 0; j2 < 4; ++j2){
            float xa = xs[k0 + 2*j2    ][nloc] * inv;
            float xb = xs[k0 + 2*j2 + 1][nloc] * inv;
            unsigned short ha = f2bf(xa), hb = f2bf(xb);
            unsigned short la = f2bf(xa - bf2f(ha)), lb = f2bf(xb - bf2f(hb));
            hu[j2] = (unsigned)ha | ((unsigned)hb << 16);
            lu[j2] = (unsigned)la | ((unsigned)lb << 16);
        }
        int nt = d*2 + rt;
        unsigned base = (unsigned)(((p*NTILE + nt)*2 + ks)*2)*256 + l*4;
        *(uint4*)&wsu[base]       = make_uint4(hu[0], hu[1], hu[2], hu[3]);
        *(uint4*)&wsu[base + 256] = make_uint4(lu[0], lu[1], lu[2], lu[3]);
    }
    if (t < 32){
        int n = d*32 + t;
        if (n < NKP) out[NPAIR*NKP*2 + p*NKP + n] = ksc[tgt*NKP + n];
    }
    if (d == 0 && t == 0){
        out[NPAIR*NKP*3 + p]         = (float)tgt;
        out[NPAIR*NKP*3 + NPAIR + p] = (float)src_ids[p];
    }
}

/* one block per (pair, 256-pixel row). Pixels = A operand (rows), keypoints
   = B operand (cols). Each wave owns 64 pixels (4 m-tiles) so the streamed
   B-fragments amortize over 2x the output vs the 32-px version — the main
   loop was B-load-BW bound, not MFMA bound. 256 px staged in two 128-px
   chunks reusing one 32KB LDS buffer; buffer is dead after the A-cache
   loads and is reused for wave-partials. */
__global__ __launch_bounds__(256, 2) void match_kernel(
    const float* __restrict__ dd, const int* __restrict__ src_ids,
    const unsigned* __restrict__ wsu, float* __restrict__ part)
{
    __shared__ unsigned lds[8192];    // staging: hi [0,4096), lo [4096,8192); later wave-partials
    __shared__ float ssp[256];
    __shared__ float invn_s[256];
    int mb = blockIdx.x, p = blockIdx.y, t = threadIdx.x;
    int w = t >> 6, l = t & 63;
    int g = l >> 4;

    /* B prefetch for nt=0,1 issues before staging (independent) */
    const unsigned* wB = wsu + (unsigned)p*28672 + (unsigned)l*4;
    uint4 Bb0[4], Bb1[4];
    #pragma unroll
    for (int k = 0; k < 4; ++k) Bb0[k] = *(const uint4*)(wB + k*256);
    #pragma unroll
    for (int k = 0; k < 4; ++k) Bb1[k] = *(const uint4*)(wB + 1024 + k*256);

    const float* plane = dd + (size_t)src_ids[p]*KDIM*HWPIX + (size_t)mb*256;

    /* two-chunk staging: thread t owns (pixel m = t&127 of chunk, k-half = t>>7);
       hi = round-half-up to bf16, lo = trunc(a - hi); v_perm packing. */
    uint4 Ac[4][4];                 // [mt][ks*2 + hi/lo]
    int m = t & 127, kh = t >> 7;
    #pragma unroll
    for (int chunk = 0; chunk < 2; ++chunk){
        unsigned sw = (unsigned)(m & 7);
        float ssum = 0.f;
        const float* cp = plane + chunk*128 + m + (size_t)kh*32*HWPIX;
        #pragma unroll
        for (int s2l = 0; s2l < 4; ++s2l){
            float v[8];
            #pragma unroll
            for (int j = 0; j < 8; ++j) v[j] = cp[(size_t)(s2l*8 + j)*HWPIX];
            unsigned hq[4], lq[4];
            #pragma unroll
            for (int q = 0; q < 4; ++q){
                float a = v[2*q], b = v[2*q+1];
                ssum = fmaf(a, a, ssum);
                ssum = fmaf(b, b, ssum);
                unsigned ta = (__builtin_bit_cast(unsigned, a) + 0x8000u) & 0xFFFF0000u;
                unsigned tb = (__builtin_bit_cast(unsigned, b) + 0x8000u) & 0xFFFF0000u;
                float la = a - __builtin_bit_cast(float, ta);
                float lb = b - __builtin_bit_cast(float, tb);
                hq[q] = __builtin_amdgcn_perm(tb, ta, 0x07060302u);
                lq[q] = __builtin_amdgcn_perm(__builtin_bit_cast(unsigned, lb),
                                              __builtin_bit_cast(unsigned, la), 0x07060302u);
            }
            unsigned slot = ((unsigned)(kh*4 + s2l)) ^ sw;
            unsigned dwb = (unsigned)m*32 + slot*4;
            *(uint4*)&lds[dwb]        = make_uint4(hq[0], hq[1], hq[2], hq[3]);
            *(uint4*)&lds[4096 + dwb] = make_uint4(lq[0], lq[1], lq[2], lq[3]);
        }
        ssp[t] = ssum;
        __syncthreads();
        if (t < 128)
            invn_s[chunk*128 + t] =
                (100.f * LOG2E) / fmaxf(sqrtf(ssp[t] + ssp[t + 128]), 1e-12f);
        /* A-cache: waves 0,1 own chunk 0 (px 0..127), waves 2,3 own chunk 1 */
        if ((w >> 1) == chunk){
            int lw = (w & 1)*64;
            #pragma unroll
            for (int mt = 0; mt < 4; ++mt){
                unsigned mm = (unsigned)(lw + mt*16 + (l & 15));
                unsigned sw2 = mm & 7;
                #pragma unroll
                for (int k = 0; k < 4; ++k){
                    unsigned slot = (((unsigned)(k >> 1))*4 + (unsigned)g) ^ sw2;
                    Ac[mt][k] = *(const uint4*)&lds[(unsigned)(k & 1)*4096 + mm*32 + slot*4];
                }
            }
        }
        __syncthreads();   /* staging LDS dead for all waves after last chunk */
    }

    const float mref2 = MREF * LOG2E;
    float invm8[4][4], ub_[4];
    int mloc0 = w*64;
    #pragma unroll
    for (int mt = 0; mt < 4; ++mt){
        ub_[mt] = (float)(mloc0 + mt*16 + g*4);
        #pragma unroll
        for (int r = 0; r < 4; ++r)
            invm8[mt][r] = invn_s[mloc0 + mt*16 + g*4 + r];
    }

    f32x4 acc0[4], acc1[4];
    float* wp = (float*)lds;        /* wave-partials [w][nt][cl] float2 (3584 dw) */

    auto zacc = [&](f32x4* a){
        #pragma unroll
        for (int mt = 0; mt < 4; ++mt) a[mt] = (f32x4){0.f,0.f,0.f,0.f};
    };
    auto unit = [&](const uint4* Bq, f32x4* a4){
        #pragma unroll
        for (int ks = 0; ks < 2; ++ks){
            frag_ab bH = __builtin_bit_cast(frag_ab, Bq[ks*2]);
            frag_ab bL = __builtin_bit_cast(frag_ab, Bq[ks*2 + 1]);
            #pragma unroll
            for (int mt = 0; mt < 4; ++mt){
                frag_ab aH = __builtin_bit_cast(frag_ab, Ac[mt][ks*2]);
                a4[mt] = __builtin_amdgcn_mfma_f32_16x16x32_bf16(aH, bH, a4[mt], 0, 0, 0);
            }
            #pragma unroll
            for (int mt = 0; mt < 4; ++mt){
                frag_ab aH = __builtin_bit_cast(frag_ab, Ac[mt][ks*2]);
                a4[mt] = __builtin_amdgcn_mfma_f32_16x16x32_bf16(aH, bL, a4[mt], 0, 0, 0);
            }
            #pragma unroll
            for (int mt = 0; mt < 4; ++mt){
                frag_ab aL = __builtin_bit_cast(frag_ab, Ac[mt][ks*2 + 1]);
                a4[mt] = __builtin_amdgcn_mfma_f32_16x16x32_bf16(aL, bH, a4[mt], 0, 0, 0);
            }
        }
    };
    auto loadB = [&](int nt, uint4* B){
        const unsigned* q = wB + (unsigned)nt*1024;
        #pragma unroll
        for (int k = 0; k < 4; ++k) B[k] = *(const uint4*)(q + k*256);
    };
    auto epi = [&](const f32x4* a4, int nt){
        float Ssum = 0.f, Usum = 0.f;
        #pragma unroll
        for (int mt = 0; mt < 4; ++mt){
            float e0 = __builtin_amdgcn_exp2f(fmaf(a4[mt][0], invm8[mt][0], -mref2));
            float e1 = __builtin_amdgcn_exp2f(fmaf(a4[mt][1], invm8[mt][1], -mref2));
            float e2 = __builtin_amdgcn_exp2f(fmaf(a4[mt][2], invm8[mt][2], -mref2));
            float e3 = __builtin_amdgcn_exp2f(fmaf(a4[mt][3], invm8[mt][3], -mref2));
            float Sm = (e0 + e1) + (e2 + e3);
            float Um = fmaf(e2, 2.f, e1);
            Um = fmaf(e3, 3.f, Um);
            Um = fmaf(ub_[mt], Sm, Um);
            Ssum += Sm; Usum += Um;
        }
        Ssum += __shfl_xor(Ssum, 16); Usum += __shfl_xor(Usum, 16);
        Ssum += __shfl_xor(Ssum, 32); Usum += __shfl_xor(Usum, 32);
        if (l < 16)
            *(float2*)&wp[((unsigned)(w*NTILE + nt)*16 + (unsigned)l)*2] =
                make_float2(Ssum, Usum);
    };

    /* pipeline over nt = 0..27 */
    zacc(acc0); unit(Bb0, acc0);                 // nt=0
    #pragma unroll 1
    for (int jj = 0; jj < 13; ++jj){
        loadB(2*jj + 2, Bb0);
        zacc(acc1); unit(Bb1, acc1);             // nt=2jj+1
        epi(acc0, 2*jj);
        loadB(2*jj + 3, Bb1);
        zacc(acc0); unit(Bb0, acc0);             // nt=2jj+2
        epi(acc1, 2*jj + 1);
    }
    zacc(acc1); unit(Bb1, acc1);                 // nt=27
    epi(acc0, 26);
    epi(acc1, 27);

    /* cross-wave sum of the 4 wave-partials -> global compact partials */
    __syncthreads();
    for (int idx = t; idx < NTILE*16; idx += 256){
        int nt = idx >> 4, cl = idx & 15;
        float S = 0.f, U = 0.f;
        #pragma unroll
        for (int ww = 0; ww < 4; ++ww){
            float2 q = *(const float2*)&wp[((unsigned)(ww*NTILE + nt)*16 + (unsigned)cl)*2];
            S += q.x; U += q.y;
        }
        *(float2*)&part[(((size_t)p*NTILE + nt)*MBLK + mb)*32 + cl*2] =
            make_float2(S, U);
    }
}

/* one block per (p, nt<25): fully-coalesced float2 reads, LDS cross-wave sum.
   mb is now the full row index v; u needs no parity correction. */
__global__ __launch_bounds__(256) void merge_kernel(
    const float* __restrict__ part, float* __restrict__ out)
{
    __shared__ float red[3][4][16];
    int nt = blockIdx.x, p = blockIdx.y, t = threadIdx.x;
    int j = t & 15, mb0 = t >> 4;
    const float* base = part + (size_t)(p*NTILE + nt)*MBLK*32;
    float S = 0.f, U = 0.f, V = 0.f;
    #pragma unroll 4
    for (int k = 0; k < 16; ++k){
        int mbk = mb0 + k*16;
        float2 q = *(const float2*)&base[(mbk*16 + j)*2];
        S += q.x;
        U += q.y;
        V = fmaf((float)mbk, q.x, V);
    }
    S += __shfl_xor(S, 16); U += __shfl_xor(U, 16); V += __shfl_xor(V, 16);
    S += __shfl_xor(S, 32); U += __shfl_xor(U, 32); V += __shfl_xor(V, 32);
    int w = t >> 6, l = t & 63;
    if (l < 16){ red[0][w][j] = S; red[1][w][j] = U; red[2][w][j] = V; }
    __syncthreads();
    if (t < 16){
        float Sf = red[0][0][t] + red[0][1][t] + red[0][2][t] + red[0][3][t];
        float Uf = red[1][0][t] + red[1][1][t] + red[1][2][t] + red[1][3][t];
        float Vf = red[2][0][t] + red[2][1][t] + red[2][2][t] + red[2][3][t];
        int n = nt*16 + t;
        out[(p*NKP + n)*2 + 0] = Uf / Sf;
        out[(p*NKP + n)*2 + 1] = Vf / Sf;
    }
}

extern "C" void kernel_launch(void* const* d_in, const int* in_sizes, int n_in,
                              void* d_out, int out_size, void* d_ws, size_t ws_size,
                              hipStream_t stream)
{
    const float* ksc     = (const float*)d_in[0];  // keypoint_scores [4,1,400]
    const float* kd      = (const float*)d_in[1];  // keypoint_desc  [4,64,400]
    const float* dd      = (const float*)d_in[2];  // desc_dense     [4,64,256,256]
    const int*   tgt_ids = (const int*)d_in[3];
    const int*   src_ids = (const int*)d_in[4];
    float* out = (float*)d_out;
    unsigned* wsu = (unsigned*)d_ws;
    float* part = (float*)d_ws + BFRAG_DW;

    prep_kernel <<<dim3(14, NPAIR),   256, 0, stream>>>(ksc, kd, tgt_ids, src_ids, wsu, out);
    match_kernel<<<dim3(MBLK, NPAIR), 256, 0, stream>>>(dd, src_ids, wsu, part);
    merge_kernel<<<dim3(25, NPAIR),   256, 0, stream>>>(part, out);
}

// Round 2
// 126.015 us; speedup vs baseline: 1.0082x; 1.0001x over previous
//
#include <hip/hip_runtime.h>
#include <math.h>

#define NPAIR  2
#define KDIM   64
#define NKP    400
#define NTILE  28            /* keypoint 16-tiles (448 padded) */
#define HWPIX  65536
#define MREF   70.0f         /* fixed softmax reference: logits = 100*cos <= 100 */
#define LOG2E  1.44269504f
#define MBLK   256           /* match blocks per pair: 256 pixels = one image row */

/* ws layout (dwords):
   [0, BFRAG_DW)  : tgt B-fragments [p][nt][ks][hi/lo][lane][4dw], bf16 pairs
   [BFRAG_DW, ..) : partials [p][nt][256 mb][16 j] float2 {S, U(full-row u)} */
#define BFRAG_DW (NPAIR*NTILE*2*2*256)   /* 57344 dwords */

using frag_ab = __attribute__((ext_vector_type(8))) short;   // 8 bf16
using f32x4   = __attribute__((ext_vector_type(4))) float;

__device__ __forceinline__ unsigned short f2bf(float f){
    unsigned u = __builtin_bit_cast(unsigned, f);
    u += 0x7fffu + ((u >> 16) & 1u);          // round-to-nearest-even
    return (unsigned short)(u >> 16);
}
__device__ __forceinline__ float bf2f(unsigned short h){
    unsigned u = ((unsigned)h) << 16;
    return __builtin_bit_cast(float, u);
}

/* normalize tgt desc, split to bf16 hi/lo, store in MFMA B-frag order
   (n = lane&15, k = (lane>>4)*8 + j). */
__global__ __launch_bounds__(256) void prep_kernel(
    const float* __restrict__ ksc, const float* __restrict__ kd,
    const int* __restrict__ tgt_ids, const int* __restrict__ src_ids,
    unsigned* __restrict__ wsu, float* __restrict__ out)
{
    __shared__ float xs[KDIM][33];
    __shared__ float inv_s[32];
    int d = blockIdx.x, p = blockIdx.y, t = threadIdx.x;
    int tgt = tgt_ids[p];
    int nl = t & 31, c0 = t >> 5;
    #pragma unroll
    for (int cc = 0; cc < 8; ++cc){
        int c = cc*8 + c0;
        int n = d*32 + nl;
        xs[c][nl] = (n < NKP) ? kd[(tgt*KDIM + c)*NKP + n] : 0.f;
    }
    __syncthreads();
    if (t < 32){
        float s = 0.f;
        #pragma unroll
        for (int c = 0; c < KDIM; ++c){ float v = xs[c][t]; s = fmaf(v, v, s); }
        inv_s[t] = 1.f / fmaxf(sqrtf(s), 1e-12f);
    }
    __syncthreads();
    {
        int l = t & 63, rk = t >> 6;
        int rt = rk >> 1, ks = rk & 1;
        int cl = l & 15, g = l >> 4;
        int nloc = rt*16 + cl;
        float inv = inv_s[nloc];
        int k0 = ks*32 + g*8;
        unsigned hu[4], lu[4];
        #pragma unroll
        for (int j2 = 0; j2 < 4; ++j2){
            float xa = xs[k0 + 2*j2    ][nloc] * inv;
            float xb = xs[k0 + 2*j2 + 1][nloc] * inv;
            unsigned short ha = f2bf(xa), hb = f2bf(xb);
            unsigned short la = f2bf(xa - bf2f(ha)), lb = f2bf(xb - bf2f(hb));
            hu[j2] = (unsigned)ha | ((unsigned)hb << 16);
            lu[j2] = (unsigned)la | ((unsigned)lb << 16);
        }
        int nt = d*2 + rt;
        unsigned base = (unsigned)(((p*NTILE + nt)*2 + ks)*2)*256 + l*4;
        *(uint4*)&wsu[base]       = make_uint4(hu[0], hu[1], hu[2], hu[3]);
        *(uint4*)&wsu[base + 256] = make_uint4(lu[0], lu[1], lu[2], lu[3]);
    }
    if (t < 32){
        int n = d*32 + t;
        if (n < NKP) out[NPAIR*NKP*2 + p*NKP + n] = ksc[tgt*NKP + n];
    }
    if (d == 0 && t == 0){
        out[NPAIR*NKP*3 + p]         = (float)tgt;
        out[NPAIR*NKP*3 + NPAIR + p] = (float)src_ids[p];
    }
}

/* one block per (pair, 256-pixel row). Pixels = A operand (rows), keypoints
   = B operand (cols). Each wave owns 64 pixels (4 m-tiles).
   A-fragments load DIRECTLY global->register in MFMA layout: for (mt,ks,j)
   lane l reads pixel (wbase + mt*16 + (l&15)), channel (ks*32 + (l>>4)*8 + j).
   Each 16-lane group consumes one full 64B line -> zero overfetch, zero
   staging LDS, zero mid-kernel barriers. Per-pixel norm (applied to logits,
   not A) recovered wave-locally: shfl_xor over the 4 k-groups, then shfl
   redistribution to accumulator-row lanes. */
__global__ __launch_bounds__(256, 2) void match_kernel(
    const float* __restrict__ dd, const int* __restrict__ src_ids,
    const unsigned* __restrict__ wsu, float* __restrict__ part)
{
    __shared__ float wp[4*NTILE*16*2];   /* wave-partials [w][nt][cl] float2 */
    int mb = blockIdx.x, p = blockIdx.y, t = threadIdx.x;
    int w = t >> 6, l = t & 63;
    int g = l >> 4, c15 = l & 15;

    /* B prefetch for nt=0,1 (L2-resident after first blocks) */
    const unsigned* wB = wsu + (unsigned)p*28672 + (unsigned)l*4;
    uint4 Bb0[4], Bb1[4];
    #pragma unroll
    for (int k = 0; k < 4; ++k) Bb0[k] = *(const uint4*)(wB + k*256);
    #pragma unroll
    for (int k = 0; k < 4; ++k) Bb1[k] = *(const uint4*)(wB + 1024 + k*256);

    const float* plane = dd + (size_t)src_ids[p]*KDIM*HWPIX;
    int wbase = mb*256 + w*64;

    /* direct A-fragment load + hi/lo split + wave-local norm */
    uint4 Ac[4][4];                 /* [mt][ks*2 + hi/lo] */
    float invv[4];
    #pragma unroll
    for (int mt = 0; mt < 4; ++mt){
        const float* ap = plane + (size_t)(g*8)*HWPIX
                        + (unsigned)(wbase + mt*16 + c15);
        float v[2][8];
        #pragma unroll
        for (int ks = 0; ks < 2; ++ks)
            #pragma unroll
            for (int j = 0; j < 8; ++j)
                v[ks][j] = ap[(size_t)(ks*32 + j)*HWPIX];
        float ssum = 0.f;
        #pragma unroll
        for (int ks = 0; ks < 2; ++ks){
            unsigned hq[4], lq[4];
            #pragma unroll
            for (int q = 0; q < 4; ++q){
                float a = v[ks][2*q], b = v[ks][2*q+1];
                ssum = fmaf(a, a, ssum);
                ssum = fmaf(b, b, ssum);
                unsigned ta = (__builtin_bit_cast(unsigned, a) + 0x8000u) & 0xFFFF0000u;
                unsigned tb = (__builtin_bit_cast(unsigned, b) + 0x8000u) & 0xFFFF0000u;
                float la = a - __builtin_bit_cast(float, ta);
                float lb = b - __builtin_bit_cast(float, tb);
                hq[q] = __builtin_amdgcn_perm(tb, ta, 0x07060302u);
                lq[q] = __builtin_amdgcn_perm(__builtin_bit_cast(unsigned, lb),
                                              __builtin_bit_cast(unsigned, la), 0x07060302u);
            }
            Ac[mt][ks*2    ] = make_uint4(hq[0], hq[1], hq[2], hq[3]);
            Ac[mt][ks*2 + 1] = make_uint4(lq[0], lq[1], lq[2], lq[3]);
        }
        /* lane holds 16-channel partial of pixel (mt, c15); sum over k-groups */
        ssum += __shfl_xor(ssum, 16);
        ssum += __shfl_xor(ssum, 32);
        invv[mt] = (100.f * LOG2E) / fmaxf(sqrtf(ssum), 1e-12f);
    }
    /* redistribute: accumulator row r of lane l is pixel (mt, g*4+r),
       whose inv lives in any lane with (lane&15)==g*4+r */
    const float mref2 = MREF * LOG2E;
    float invm8[4][4], ub_[4];
    #pragma unroll
    for (int mt = 0; mt < 4; ++mt){
        ub_[mt] = (float)(w*64 + mt*16 + g*4);
        #pragma unroll
        for (int r = 0; r < 4; ++r)
            invm8[mt][r] = __shfl(invv[mt], (l & 48) | (g*4 + r));
    }

    f32x4 acc0[4], acc1[4];

    auto zacc = [&](f32x4* a){
        #pragma unroll
        for (int mt = 0; mt < 4; ++mt) a[mt] = (f32x4){0.f,0.f,0.f,0.f};
    };
    auto unit = [&](const uint4* Bq, f32x4* a4){
        #pragma unroll
        for (int ks = 0; ks < 2; ++ks){
            frag_ab bH = __builtin_bit_cast(frag_ab, Bq[ks*2]);
            frag_ab bL = __builtin_bit_cast(frag_ab, Bq[ks*2 + 1]);
            #pragma unroll
            for (int mt = 0; mt < 4; ++mt){
                frag_ab aH = __builtin_bit_cast(frag_ab, Ac[mt][ks*2]);
                a4[mt] = __builtin_amdgcn_mfma_f32_16x16x32_bf16(aH, bH, a4[mt], 0, 0, 0);
            }
            #pragma unroll
            for (int mt = 0; mt < 4; ++mt){
                frag_ab aH = __builtin_bit_cast(frag_ab, Ac[mt][ks*2]);
                a4[mt] = __builtin_amdgcn_mfma_f32_16x16x32_bf16(aH, bL, a4[mt], 0, 0, 0);
            }
            #pragma unroll
            for (int mt = 0; mt < 4; ++mt){
                frag_ab aL = __builtin_bit_cast(frag_ab, Ac[mt][ks*2 + 1]);
                a4[mt] = __builtin_amdgcn_mfma_f32_16x16x32_bf16(aL, bH, a4[mt], 0, 0, 0);
            }
        }
    };
    auto loadB = [&](int nt, uint4* B){
        const unsigned* q = wB + (unsigned)nt*1024;
        #pragma unroll
        for (int k = 0; k < 4; ++k) B[k] = *(const uint4*)(q + k*256);
    };
    auto epi = [&](const f32x4* a4, int nt){
        float Ssum = 0.f, Usum = 0.f;
        #pragma unroll
        for (int mt = 0; mt < 4; ++mt){
            float e0 = __builtin_amdgcn_exp2f(fmaf(a4[mt][0], invm8[mt][0], -mref2));
            float e1 = __builtin_amdgcn_exp2f(fmaf(a4[mt][1], invm8[mt][1], -mref2));
            float e2 = __builtin_amdgcn_exp2f(fmaf(a4[mt][2], invm8[mt][2], -mref2));
            float e3 = __builtin_amdgcn_exp2f(fmaf(a4[mt][3], invm8[mt][3], -mref2));
            float Sm = (e0 + e1) + (e2 + e3);
            float Um = fmaf(e2, 2.f, e1);
            Um = fmaf(e3, 3.f, Um);
            Um = fmaf(ub_[mt], Sm, Um);
            Ssum += Sm; Usum += Um;
        }
        Ssum += __shfl_xor(Ssum, 16); Usum += __shfl_xor(Usum, 16);
        Ssum += __shfl_xor(Ssum, 32); Usum += __shfl_xor(Usum, 32);
        if (l < 16)
            *(float2*)&wp[((unsigned)(w*NTILE + nt)*16 + (unsigned)l)*2] =
                make_float2(Ssum, Usum);
    };

    /* pipeline over nt = 0..27 */
    zacc(acc0); unit(Bb0, acc0);                 // nt=0
    #pragma unroll 1
    for (int jj = 0; jj < 13; ++jj){
        loadB(2*jj + 2, Bb0);
        zacc(acc1); unit(Bb1, acc1);             // nt=2jj+1
        epi(acc0, 2*jj);
        loadB(2*jj + 3, Bb1);
        zacc(acc0); unit(Bb0, acc0);             // nt=2jj+2
        epi(acc1, 2*jj + 1);
    }
    zacc(acc1); unit(Bb1, acc1);                 // nt=27
    epi(acc0, 26);
    epi(acc1, 27);

    /* cross-wave sum of the 4 wave-partials -> global compact partials */
    __syncthreads();
    for (int idx = t; idx < NTILE*16; idx += 256){
        int nt = idx >> 4, cl = idx & 15;
        float S = 0.f, U = 0.f;
        #pragma unroll
        for (int ww = 0; ww < 4; ++ww){
            float2 q = *(const float2*)&wp[((unsigned)(ww*NTILE + nt)*16 + (unsigned)cl)*2];
            S += q.x; U += q.y;
        }
        *(float2*)&part[(((size_t)p*NTILE + nt)*MBLK + mb)*32 + cl*2] =
            make_float2(S, U);
    }
}

/* one block per (p, nt<25): fully-coalesced float2 reads, LDS cross-wave sum.
   mb is the full row index v; u needs no parity correction. */
__global__ __launch_bounds__(256) void merge_kernel(
    const float* __restrict__ part, float* __restrict__ out)
{
    __shared__ float red[3][4][16];
    int nt = blockIdx.x, p = blockIdx.y, t = threadIdx.x;
    int j = t & 15, mb0 = t >> 4;
    const float* base = part + (size_t)(p*NTILE + nt)*MBLK*32;
    float S = 0.f, U = 0.f, V = 0.f;
    #pragma unroll 4
    for (int k = 0; k < 16; ++k){
        int mbk = mb0 + k*16;
        float2 q = *(const float2*)&base[(mbk*16 + j)*2];
        S += q.x;
        U += q.y;
        V = fmaf((float)mbk, q.x, V);
    }
    S += __shfl_xor(S, 16); U += __shfl_xor(U, 16); V += __shfl_xor(V, 16);
    S += __shfl_xor(S, 32); U += __shfl_xor(U, 32); V += __shfl_xor(V, 32);
    int w = t >> 6, l = t & 63;
    if (l < 16){ red[0][w][j] = S; red[1][w][j] = U; red[2][w][j] = V; }
    __syncthreads();
    if (t < 16){
        float Sf = red[0][0][t] + red[0][1][t] + red[0][2][t] + red[0][3][t];
        float Uf = red[1][0][t] + red[1][1][t] + red[1][2][t] + red[1][3][t];
        float Vf = red[2][0][t] + red[2][1][t] + red[2][2][t] + red[2][3][t];
        int n = nt*16 + t;
        out[(p*NKP + n)*2 + 0] = Uf / Sf;
        out[(p*NKP + n)*2 + 1] = Vf / Sf;
    }
}

extern "C" void kernel_launch(void* const* d_in, const int* in_sizes, int n_in,
                              void* d_out, int out_size, void* d_ws, size_t ws_size,
                              hipStream_t stream)
{
    const float* ksc     = (const float*)d_in[0];  // keypoint_scores [4,1,400]
    const float* kd      = (const float*)d_in[1];  // keypoint_desc  [4,64,400]
    const float* dd      = (const float*)d_in[2];  // desc_dense     [4,64,256,256]
    const int*   tgt_ids = (const int*)d_in[3];
    const int*   src_ids = (const int*)d_in[4];
    float* out = (float*)d_out;
    unsigned* wsu = (unsigned*)d_ws;
    float* part = (float*)d_ws + BFRAG_DW;

    prep_kernel <<<dim3(14, NPAIR),   256, 0, stream>>>(ksc, kd, tgt_ids, src_ids, wsu, out);
    match_kernel<<<dim3(MBLK, NPAIR), 256, 0, stream>>>(dd, src_ids, wsu, part);
    merge_kernel<<<dim3(25, NPAIR),   256, 0, stream>>>(part, out);
}